// Round 10
// baseline (3142.124 us; speedup 1.0000x reference)
//
#include <hip/hip_runtime.h>
#include <math.h>

typedef _Float16 f16;
typedef f16  f16x8 __attribute__((ext_vector_type(8)));
typedef f16  f16x4 __attribute__((ext_vector_type(4)));
typedef float f32x4 __attribute__((ext_vector_type(4)));

#define NB 64
#define NC 16
#define NF 128
#define ND 256
#define NSTEP 60
#define GRID_ELEMS (NB*64*64*NC)   // 16 MB fp32
#define NPIX (NB*64*64)

#define KCONV 160                  // 9 taps * 16ch padded to 10 taps
#define HSS   136                  // hs row stride (f16)
#define RPS   20                   // redF row stride (fp32): kills 4-way q-conflict

// weight buffer layout (f16 elements) inside d_out scratch region
#define OFF_CW 0             // [128][160]
#define OFF_W1 20480         // [256][128]
#define OFF_W2 53248         // [16][256]

// ---------------- init: grid ch0 = input, others 0 ----------------
__global__ void init_grid(const float* __restrict__ inp, float* __restrict__ g) {
    int i = blockIdx.x * 256 + threadIdx.x;
    if (i >= GRID_ELEMS) return;
    int c = i & 15;
    g[i] = (c == 0) ? inp[i >> 4] : 0.0f;
}

// ---------------- prep: f16 transposed weights ----------------
__global__ void prep_weights(const float* __restrict__ cw, const float* __restrict__ w1,
                             const float* __restrict__ w2, f16* __restrict__ wb) {
    int i = blockIdx.x * 256 + threadIdx.x;   // 57344 threads exactly
    float v; int off, idx;
    if (i < 20480) {                          // cwT[f][k], k = tap*16+c (tap9 zero)
        int f = i / 160, k = i - f * 160;
        v = (k < 144) ? cw[k * 128 + f] : 0.0f;
        off = OFF_CW; idx = i;
    } else if (i < 20480 + 32768) {           // w1T[j][f]
        int r = i - 20480;
        int j = r >> 7, f = r & 127;
        v = w1[f * 256 + j];
        off = OFF_W1; idx = r;
    } else {                                  // w2T[c][j]
        int r = i - 20480 - 32768;
        int c = r >> 8, j = r & 255;
        v = w2[j * 16 + c];
        off = OFF_W2; idx = r;
    }
    wb[off + idx] = (f16)v;
}

// ---------------- fused NCA step (pure-f16 MFMA, fp32 accumulate/state) ----------------
// Block = 8x16 px tile (128 px), 256 threads = 4 waves, 4 blocks/CU (40960 B LDS).
// R9-proven structure. Operand-swapped matmuls D'[out][px] = W[out][k] * X[k][px];
// dense j-split across waves with cross-wave LDS reduction (redF stride 20: 2-way).
__global__ __launch_bounds__(256, 4) void nca_step(
    const float* __restrict__ gin, float* __restrict__ gout,
    const f16* __restrict__ wb,
    const float* __restrict__ cb, const float* __restrict__ b1, const float* __restrict__ b2)
{
    // hs[128*136] (34816 B) + union{ halo [10*18][16] (5760 B) | aScr [64][40] (5120 B) }
    // redF (4*128*20 fp32 = 40960 B) overlays everything after dense phase.
    __shared__ f16 smem[20480];              // 40960 B exactly -> 4 blocks/CU
    f16* const hs   = smem;                  // 17408 elems
    f16* const un   = smem + 17408;
    f16* const halo = un;                    // [(yy*18+xx)]*16 + c
    f16* const aScr = un;                    // [4w*16px][40]
    float* const redF = (float*)smem;        // [4][128][RPS] fp32

    const int t    = threadIdx.x;
    const int w    = t >> 6;
    const int lane = t & 63;
    const int q    = lane >> 4;
    const int l16  = lane & 15;

    const int bi = blockIdx.x;
    const int b  = bi >> 5;
    const int tl = bi & 31;
    const int y0 = (tl >> 2) << 3;
    const int x0 = (tl & 3) << 4;

    const float* gb  = gin  + (size_t)b * 64 * 64 * 16;
    float*       gob = gout + (size_t)b * 64 * 64 * 16;

    // ---- conv A-fragments + w2 fragments: issue global loads first ----
    const int fbase = w << 5;                // wave owns 32 filters
    f16x8 cA[2][5];
    #pragma unroll
    for (int ft = 0; ft < 2; ++ft)
        #pragma unroll
        for (int kc = 0; kc < 5; ++kc)
            cA[ft][kc] = *(const f16x8*)(wb + OFF_CW +
                (size_t)(fbase + ft * 16 + l16) * KCONV + kc * 32 + q * 8);
    const int jbase = w << 6;                // wave owns 64 j-columns
    f16x8 w2f[2];
    #pragma unroll
    for (int jp = 0; jp < 2; ++jp)
        w2f[jp] = *(const f16x8*)(wb + OFF_W2 + (size_t)l16 * 256 + jbase + jp * 32 + q * 8);

    // ---- stage halo (f16), zero-pad SAME ----
    for (int i = t; i < 720; i += 256) {     // 180 cells x 4 c-quads
        int c4 = (i & 3) << 2;
        int xy = i >> 2;
        int xx = xy % 18;
        int yy = xy / 18;
        int gy = y0 + yy - 1, gx = x0 + xx - 1;
        f32x4 v = {0.f, 0.f, 0.f, 0.f};
        if ((unsigned)gy < 64u && (unsigned)gx < 64u)
            v = *(const f32x4*)(gb + (gy * 64 + gx) * 16 + c4);
        f16x4 hv;
        hv.x = (f16)v.x; hv.y = (f16)v.y; hv.z = (f16)v.z; hv.w = (f16)v.w;
        *(f16x4*)(halo + (yy * 18 + xx) * 16 + c4) = hv;
    }
    __syncthreads();

    // ================= conv 3x3x16 -> 128, bias, relu =================
    f32x4 acc[2][8];
    #pragma unroll
    for (int ft = 0; ft < 2; ++ft) {
        f32x4 bias;
        bias.x = cb[fbase + ft * 16 + q * 4 + 0];
        bias.y = cb[fbase + ft * 16 + q * 4 + 1];
        bias.z = cb[fbase + ft * 16 + q * 4 + 2];
        bias.w = cb[fbase + ft * 16 + q * 4 + 3];
        #pragma unroll
        for (int p = 0; p < 8; ++p) acc[ft][p] = bias;
    }

    #pragma unroll
    for (int kc = 0; kc < 5; ++kc) {
        int tap = kc * 2 + (q >> 1);
        if (tap > 8) tap = 8;                // k>=144: weights are zero
        int dy = tap / 3, dx = tap - dy * 3;
        int boff = dy * 288 + (l16 + dx) * 16 + (q & 1) * 8;
        #pragma unroll
        for (int p = 0; p < 8; ++p) {
            f16x8 bf = *(const f16x8*)(halo + boff + p * 288);
            #pragma unroll
            for (int ft = 0; ft < 2; ++ft)
                acc[ft][p] = __builtin_amdgcn_mfma_f32_16x16x32_f16(cA[ft][kc], bf, acc[ft][p], 0, 0, 0);
        }
    }

    // relu in fp32, pack f16, write hs[px][f] (b64)
    #pragma unroll
    for (int ft = 0; ft < 2; ++ft)
        #pragma unroll
        for (int p = 0; p < 8; ++p) {
            f32x4 a = acc[ft][p];
            f16x4 pk;
            pk.x = (f16)fmaxf(a.x, 0.0f);
            pk.y = (f16)fmaxf(a.y, 0.0f);
            pk.z = (f16)fmaxf(a.z, 0.0f);
            pk.w = (f16)fmaxf(a.w, 0.0f);
            *(f16x4*)(hs + (p * 16 + l16) * HSS + fbase + ft * 16 + q * 4) = pk;
        }
    __syncthreads();   // hs published; halo region dead -> aScr

    // ============ dense1 (128->256, relu) fused w/ dense2 (256->16) ============
    f32x4 dacc[8];   // PARTIAL over this wave's 64 j
    #pragma unroll
    for (int p = 0; p < 8; ++p) { dacc[p].x = 0.f; dacc[p].y = 0.f; dacc[p].z = 0.f; dacc[p].w = 0.f; }

    f16* const myScr = aScr + (w * 16 + l16) * 40;

    for (int jp = 0; jp < 2; ++jp) {
        f16x8 dA[2][4];
        #pragma unroll
        for (int jt2 = 0; jt2 < 2; ++jt2)
            #pragma unroll
            for (int kc = 0; kc < 4; ++kc)
                dA[jt2][kc] = *(const f16x8*)(wb + OFF_W1 +
                    (size_t)(jbase + jp * 32 + jt2 * 16 + l16) * 128 + kc * 32 + q * 8);
        float b1v[2][4];
        #pragma unroll
        for (int jt2 = 0; jt2 < 2; ++jt2)
            #pragma unroll
            for (int r = 0; r < 4; ++r)
                b1v[jt2][r] = b1[jbase + jp * 32 + jt2 * 16 + q * 4 + r];

        for (int p = 0; p < 8; ++p) {
            f16x8 hB[4];
            #pragma unroll
            for (int kc = 0; kc < 4; ++kc)
                hB[kc] = *(const f16x8*)(hs + (p * 16 + l16) * HSS + kc * 32 + q * 8);

            #pragma unroll
            for (int jt2 = 0; jt2 < 2; ++jt2) {
                f32x4 a1;
                a1.x = b1v[jt2][0]; a1.y = b1v[jt2][1];
                a1.z = b1v[jt2][2]; a1.w = b1v[jt2][3];
                #pragma unroll
                for (int kc = 0; kc < 4; ++kc)
                    a1 = __builtin_amdgcn_mfma_f32_16x16x32_f16(dA[jt2][kc], hB[kc], a1, 0, 0, 0);
                f16x4 pk;
                pk.x = (f16)fmaxf(a1.x, 0.0f);
                pk.y = (f16)fmaxf(a1.y, 0.0f);
                pk.z = (f16)fmaxf(a1.z, 0.0f);
                pk.w = (f16)fmaxf(a1.w, 0.0f);
                // D rows j32 = jt2*16+q*4+r, col px=l16 -> scratch[px][j32]
                *(f16x4*)(myScr + jt2 * 16 + q * 4) = pk;
            }
            // in-wave transpose readback: A-op [m=px=l16][k=q*8..]
            f16x8 af = *(const f16x8*)(myScr + q * 8);
            dacc[p] = __builtin_amdgcn_mfma_f32_16x16x32_f16(af, w2f[jp], dacc[p], 0, 0, 0);
        }
    }

    // ---- cross-wave reduction of dense2 partials ----
    __syncthreads();                         // all hs reads done -> redF may overwrite
    #pragma unroll
    for (int p = 0; p < 8; ++p)
        #pragma unroll
        for (int r = 0; r < 4; ++r) {
            int px = p * 16 + q * 4 + r;     // D row -> pixel, col l16 -> channel
            redF[(w * 128 + px) * RPS + l16] = dacc[p][r];
        }
    __syncthreads();

    // thread t: px = t>>1, channels c0..c0+7 ; masked residual update (vectorized)
    {
        const int px = t >> 1;
        const int c0 = (t & 1) * 8;
        const int yy = px >> 4, xx = px & 15;
        const size_t pixb = ((size_t)(y0 + yy) * 64 + (x0 + xx)) * 16;
        const float a0 = gb[pixb];           // exact fp32 ch0
        const bool alive = (a0 > 0.1f);
        #pragma unroll
        for (int h = 0; h < 2; ++h) {
            const int ch = c0 + h * 4;
            f32x4 v0 = *(const f32x4*)(redF + (0 * 128 + px) * RPS + ch);
            f32x4 v1 = *(const f32x4*)(redF + (1 * 128 + px) * RPS + ch);
            f32x4 v2 = *(const f32x4*)(redF + (2 * 128 + px) * RPS + ch);
            f32x4 v3 = *(const f32x4*)(redF + (3 * 128 + px) * RPS + ch);
            f32x4 sv = v0 + v1 + v2 + v3;
            f32x4 gv = *(const f32x4*)(gb + pixb + ch);
            f32x4 ov;
            #pragma unroll
            for (int i = 0; i < 4; ++i) {
                int c = ch + i;
                float nv = gv[i];
                if (alive && c != 0) nv += sv[i] + b2[c];
                ov[i] = nv;
            }
            *(f32x4*)(gob + pixb + ch) = ov;
        }
    }
}

// ---------------- final softmax over channels 1..10 ----------------
__global__ void softmax_out(const float* __restrict__ g, float* __restrict__ out) {
    int pix = blockIdx.x * 256 + threadIdx.x;
    if (pix >= NPIX) return;
    const float* gp = g + (size_t)pix * 16;
    float v[10];
    float m = -1e30f;
    #pragma unroll
    for (int i = 0; i < 10; ++i) { v[i] = gp[1 + i]; m = fmaxf(m, v[i]); }
    float s = 0.f;
    #pragma unroll
    for (int i = 0; i < 10; ++i) { v[i] = __expf(v[i] - m); s += v[i]; }
    float inv = 1.0f / s;
    float* op = out + (size_t)pix * 10;
    #pragma unroll
    for (int i = 0; i < 10; ++i) op[i] = v[i] * inv;
}

extern "C" void kernel_launch(void* const* d_in, const int* in_sizes, int n_in,
                              void* d_out, int out_size, void* d_ws, size_t ws_size,
                              hipStream_t stream) {
    const float* inp = (const float*)d_in[0];
    const float* cw  = (const float*)d_in[1];
    const float* cb  = (const float*)d_in[2];
    const float* w1  = (const float*)d_in[3];
    const float* b1  = (const float*)d_in[4];
    const float* w2  = (const float*)d_in[5];
    const float* b2  = (const float*)d_in[6];
    float* out = (float*)d_out;

    // grid double-buffer in d_ws (32 MB, proven)
    float* g0 = (float*)d_ws;
    float* g1 = g0 + GRID_ELEMS;
    // f16 weights in d_out scratch (115 KB of 10.48 MB; softmax overwrites at end)
    f16* wb = (f16*)d_out;

    prep_weights<<<224, 256, 0, stream>>>(cw, w1, w2, wb);
    init_grid<<<(GRID_ELEMS + 255) / 256, 256, 0, stream>>>(inp, g0);

    float* bufs[2] = { g0, g1 };
    for (int s = 0; s < NSTEP; ++s) {
        nca_step<<<2048, 256, 0, stream>>>(bufs[s & 1], bufs[(s + 1) & 1],
                                           wb, cb, b1, b2);
    }
    // NSTEP=60 even -> final state in g0
    softmax_out<<<(NPIX + 255) / 256, 256, 0, stream>>>(g0, out);
}

// Round 11
// 2705.070 us; speedup vs baseline: 1.1616x; 1.1616x over previous
//
#include <hip/hip_runtime.h>
#include <math.h>

typedef _Float16 f16;
typedef f16  f16x8 __attribute__((ext_vector_type(8)));
typedef f16  f16x4 __attribute__((ext_vector_type(4)));
typedef float f32x4 __attribute__((ext_vector_type(4)));

#define NB 64
#define NC 16
#define NF 128
#define ND 256
#define NSTEP 60
#define GRID_ELEMS (NB*64*64*NC)   // 16 MB fp32
#define NPIX (NB*64*64)

#define KCONV 160                  // 9 taps * 16ch padded to 10 taps
#define HSS   136                  // hs row stride (f16)
#define RPS   20                   // redF row stride (fp32): kills 4-way q-conflict

// weight buffer layout (f16 elements) inside d_out scratch region
#define OFF_CW 0             // [128][160]
#define OFF_W1 20480         // [256][128]
#define OFF_W2 53248         // [16][256]

// ---------------- init: grid ch0 = input, others 0 ----------------
__global__ void init_grid(const float* __restrict__ inp, float* __restrict__ g) {
    int i = blockIdx.x * 256 + threadIdx.x;
    if (i >= GRID_ELEMS) return;
    int c = i & 15;
    g[i] = (c == 0) ? inp[i >> 4] : 0.0f;
}

// ---------------- prep: f16 transposed weights ----------------
__global__ void prep_weights(const float* __restrict__ cw, const float* __restrict__ w1,
                             const float* __restrict__ w2, f16* __restrict__ wb) {
    int i = blockIdx.x * 256 + threadIdx.x;   // 57344 threads exactly
    float v; int off, idx;
    if (i < 20480) {                          // cwT[f][k], k = tap*16+c (tap9 zero)
        int f = i / 160, k = i - f * 160;
        v = (k < 144) ? cw[k * 128 + f] : 0.0f;
        off = OFF_CW; idx = i;
    } else if (i < 20480 + 32768) {           // w1T[j][f]
        int r = i - 20480;
        int j = r >> 7, f = r & 127;
        v = w1[f * 256 + j];
        off = OFF_W1; idx = r;
    } else {                                  // w2T[c][j]
        int r = i - 20480 - 32768;
        int c = r >> 8, j = r & 255;
        v = w2[j * 16 + c];
        off = OFF_W2; idx = r;
    }
    wb[off + idx] = (f16)v;
}

// ---------------- fused NCA step (pure-f16 MFMA, fp32 accumulate/state) ----------------
// Block = 8x16 px tile (128 px), 256 threads = 4 waves, 3 blocks/CU (no spill —
// R10 showed launch_bounds(256,4) forces VGPR 64 and ~88MB/step spill traffic).
// Dense phase is p-outer / jp-inner with all dA fragments held in registers:
// hB LDS reads drop 64 -> 32 b128 per wave. Accumulation order bit-identical to R9.
__global__ __launch_bounds__(256, 3) void nca_step(
    const float* __restrict__ gin, float* __restrict__ gout,
    const f16* __restrict__ wb,
    const float* __restrict__ cb, const float* __restrict__ b1, const float* __restrict__ b2)
{
    // hs[128*136] (34816 B) + union{ halo [10*18][16] (5760 B) | aScr [64][40] (5120 B) }
    // redF (4*128*20 fp32 = 40960 B) overlays everything after dense phase.
    __shared__ f16 smem[20480];              // 40960 B
    f16* const hs   = smem;                  // 17408 elems
    f16* const un   = smem + 17408;
    f16* const halo = un;                    // [(yy*18+xx)]*16 + c
    f16* const aScr = un;                    // [4w*16px][40]
    float* const redF = (float*)smem;        // [4][128][RPS] fp32

    const int t    = threadIdx.x;
    const int w    = t >> 6;
    const int lane = t & 63;
    const int q    = lane >> 4;
    const int l16  = lane & 15;

    const int bi = blockIdx.x;
    const int b  = bi >> 5;
    const int tl = bi & 31;
    const int y0 = (tl >> 2) << 3;
    const int x0 = (tl & 3) << 4;

    const float* gb  = gin  + (size_t)b * 64 * 64 * 16;
    float*       gob = gout + (size_t)b * 64 * 64 * 16;

    // ---- conv A-fragments + w2 fragments: issue global loads first ----
    const int fbase = w << 5;                // wave owns 32 filters
    f16x8 cA[2][5];
    #pragma unroll
    for (int ft = 0; ft < 2; ++ft)
        #pragma unroll
        for (int kc = 0; kc < 5; ++kc)
            cA[ft][kc] = *(const f16x8*)(wb + OFF_CW +
                (size_t)(fbase + ft * 16 + l16) * KCONV + kc * 32 + q * 8);
    const int jbase = w << 6;                // wave owns 64 j-columns
    f16x8 w2f[2];
    #pragma unroll
    for (int jp = 0; jp < 2; ++jp)
        w2f[jp] = *(const f16x8*)(wb + OFF_W2 + (size_t)l16 * 256 + jbase + jp * 32 + q * 8);

    // ---- stage halo (f16), zero-pad SAME ----
    for (int i = t; i < 720; i += 256) {     // 180 cells x 4 c-quads
        int c4 = (i & 3) << 2;
        int xy = i >> 2;
        int xx = xy % 18;
        int yy = xy / 18;
        int gy = y0 + yy - 1, gx = x0 + xx - 1;
        f32x4 v = {0.f, 0.f, 0.f, 0.f};
        if ((unsigned)gy < 64u && (unsigned)gx < 64u)
            v = *(const f32x4*)(gb + (gy * 64 + gx) * 16 + c4);
        f16x4 hv;
        hv.x = (f16)v.x; hv.y = (f16)v.y; hv.z = (f16)v.z; hv.w = (f16)v.w;
        *(f16x4*)(halo + (yy * 18 + xx) * 16 + c4) = hv;
    }
    __syncthreads();

    // ================= conv 3x3x16 -> 128, bias, relu =================
    f32x4 acc[2][8];
    #pragma unroll
    for (int ft = 0; ft < 2; ++ft) {
        f32x4 bias;
        bias.x = cb[fbase + ft * 16 + q * 4 + 0];
        bias.y = cb[fbase + ft * 16 + q * 4 + 1];
        bias.z = cb[fbase + ft * 16 + q * 4 + 2];
        bias.w = cb[fbase + ft * 16 + q * 4 + 3];
        #pragma unroll
        for (int p = 0; p < 8; ++p) acc[ft][p] = bias;
    }

    #pragma unroll
    for (int kc = 0; kc < 5; ++kc) {
        int tap = kc * 2 + (q >> 1);
        if (tap > 8) tap = 8;                // k>=144: weights are zero
        int dy = tap / 3, dx = tap - dy * 3;
        int boff = dy * 288 + (l16 + dx) * 16 + (q & 1) * 8;
        #pragma unroll
        for (int p = 0; p < 8; ++p) {
            f16x8 bf = *(const f16x8*)(halo + boff + p * 288);
            #pragma unroll
            for (int ft = 0; ft < 2; ++ft)
                acc[ft][p] = __builtin_amdgcn_mfma_f32_16x16x32_f16(cA[ft][kc], bf, acc[ft][p], 0, 0, 0);
        }
    }

    // relu in fp32, pack f16, write hs[px][f] (b64)
    #pragma unroll
    for (int ft = 0; ft < 2; ++ft)
        #pragma unroll
        for (int p = 0; p < 8; ++p) {
            f32x4 a = acc[ft][p];
            f16x4 pk;
            pk.x = (f16)fmaxf(a.x, 0.0f);
            pk.y = (f16)fmaxf(a.y, 0.0f);
            pk.z = (f16)fmaxf(a.z, 0.0f);
            pk.w = (f16)fmaxf(a.w, 0.0f);
            *(f16x4*)(hs + (p * 16 + l16) * HSS + fbase + ft * 16 + q * 4) = pk;
        }
    __syncthreads();   // hs published; halo region dead -> aScr

    // ============ dense1 (128->256, relu) fused w/ dense2 (256->16) ============
    // All w1 fragments for this wave's 64 j held in registers (loaded once);
    // p-outer loop reads each hB fragment from LDS exactly once.
    f16x8 dA[2][2][4];
    float b1v[2][2][4];
    #pragma unroll
    for (int jp = 0; jp < 2; ++jp)
        #pragma unroll
        for (int jt2 = 0; jt2 < 2; ++jt2) {
            #pragma unroll
            for (int kc = 0; kc < 4; ++kc)
                dA[jp][jt2][kc] = *(const f16x8*)(wb + OFF_W1 +
                    (size_t)(jbase + jp * 32 + jt2 * 16 + l16) * 128 + kc * 32 + q * 8);
            #pragma unroll
            for (int r = 0; r < 4; ++r)
                b1v[jp][jt2][r] = b1[jbase + jp * 32 + jt2 * 16 + q * 4 + r];
        }

    f32x4 dacc[8];   // PARTIAL over this wave's 64 j
    #pragma unroll
    for (int p = 0; p < 8; ++p) { dacc[p].x = 0.f; dacc[p].y = 0.f; dacc[p].z = 0.f; dacc[p].w = 0.f; }

    f16* const myScr = aScr + (w * 16 + l16) * 40;

    for (int p = 0; p < 8; ++p) {
        f16x8 hB[4];
        #pragma unroll
        for (int kc = 0; kc < 4; ++kc)
            hB[kc] = *(const f16x8*)(hs + (p * 16 + l16) * HSS + kc * 32 + q * 8);

        #pragma unroll
        for (int jp = 0; jp < 2; ++jp) {
            #pragma unroll
            for (int jt2 = 0; jt2 < 2; ++jt2) {
                f32x4 a1;
                a1.x = b1v[jp][jt2][0]; a1.y = b1v[jp][jt2][1];
                a1.z = b1v[jp][jt2][2]; a1.w = b1v[jp][jt2][3];
                #pragma unroll
                for (int kc = 0; kc < 4; ++kc)
                    a1 = __builtin_amdgcn_mfma_f32_16x16x32_f16(dA[jp][jt2][kc], hB[kc], a1, 0, 0, 0);
                f16x4 pk;
                pk.x = (f16)fmaxf(a1.x, 0.0f);
                pk.y = (f16)fmaxf(a1.y, 0.0f);
                pk.z = (f16)fmaxf(a1.z, 0.0f);
                pk.w = (f16)fmaxf(a1.w, 0.0f);
                // D rows j32 = jt2*16+q*4+r, col px=l16 -> scratch[px][j32]
                *(f16x4*)(myScr + jt2 * 16 + q * 4) = pk;
            }
            // in-wave transpose readback: A-op [m=px=l16][k=q*8..]
            f16x8 af = *(const f16x8*)(myScr + q * 8);
            dacc[p] = __builtin_amdgcn_mfma_f32_16x16x32_f16(af, w2f[jp], dacc[p], 0, 0, 0);
        }
    }

    // ---- cross-wave reduction of dense2 partials ----
    __syncthreads();                         // all hs reads done -> redF may overwrite
    #pragma unroll
    for (int p = 0; p < 8; ++p)
        #pragma unroll
        for (int r = 0; r < 4; ++r) {
            int px = p * 16 + q * 4 + r;     // D row -> pixel, col l16 -> channel
            redF[(w * 128 + px) * RPS + l16] = dacc[p][r];
        }
    __syncthreads();

    // thread t: px = t>>1, channels c0..c0+7 ; masked residual update (vectorized)
    {
        const int px = t >> 1;
        const int c0 = (t & 1) * 8;
        const int yy = px >> 4, xx = px & 15;
        const size_t pixb = ((size_t)(y0 + yy) * 64 + (x0 + xx)) * 16;
        const float a0 = gb[pixb];           // exact fp32 ch0
        const bool alive = (a0 > 0.1f);
        #pragma unroll
        for (int h = 0; h < 2; ++h) {
            const int ch = c0 + h * 4;
            f32x4 v0 = *(const f32x4*)(redF + (0 * 128 + px) * RPS + ch);
            f32x4 v1 = *(const f32x4*)(redF + (1 * 128 + px) * RPS + ch);
            f32x4 v2 = *(const f32x4*)(redF + (2 * 128 + px) * RPS + ch);
            f32x4 v3 = *(const f32x4*)(redF + (3 * 128 + px) * RPS + ch);
            f32x4 sv = v0 + v1 + v2 + v3;
            f32x4 gv = *(const f32x4*)(gb + pixb + ch);
            f32x4 ov;
            #pragma unroll
            for (int i = 0; i < 4; ++i) {
                int c = ch + i;
                float nv = gv[i];
                if (alive && c != 0) nv += sv[i] + b2[c];
                ov[i] = nv;
            }
            *(f32x4*)(gob + pixb + ch) = ov;
        }
    }
}

// ---------------- final softmax over channels 1..10 ----------------
__global__ void softmax_out(const float* __restrict__ g, float* __restrict__ out) {
    int pix = blockIdx.x * 256 + threadIdx.x;
    if (pix >= NPIX) return;
    const float* gp = g + (size_t)pix * 16;
    float v[10];
    float m = -1e30f;
    #pragma unroll
    for (int i = 0; i < 10; ++i) { v[i] = gp[1 + i]; m = fmaxf(m, v[i]); }
    float s = 0.f;
    #pragma unroll
    for (int i = 0; i < 10; ++i) { v[i] = __expf(v[i] - m); s += v[i]; }
    float inv = 1.0f / s;
    float* op = out + (size_t)pix * 10;
    #pragma unroll
    for (int i = 0; i < 10; ++i) op[i] = v[i] * inv;
}

extern "C" void kernel_launch(void* const* d_in, const int* in_sizes, int n_in,
                              void* d_out, int out_size, void* d_ws, size_t ws_size,
                              hipStream_t stream) {
    const float* inp = (const float*)d_in[0];
    const float* cw  = (const float*)d_in[1];
    const float* cb  = (const float*)d_in[2];
    const float* w1  = (const float*)d_in[3];
    const float* b1  = (const float*)d_in[4];
    const float* w2  = (const float*)d_in[5];
    const float* b2  = (const float*)d_in[6];
    float* out = (float*)d_out;

    // grid double-buffer in d_ws (32 MB, proven)
    float* g0 = (float*)d_ws;
    float* g1 = g0 + GRID_ELEMS;
    // f16 weights in d_out scratch (115 KB of 10.48 MB; softmax overwrites at end)
    f16* wb = (f16*)d_out;

    prep_weights<<<224, 256, 0, stream>>>(cw, w1, w2, wb);
    init_grid<<<(GRID_ELEMS + 255) / 256, 256, 0, stream>>>(inp, g0);

    float* bufs[2] = { g0, g1 };
    for (int s = 0; s < NSTEP; ++s) {
        nca_step<<<2048, 256, 0, stream>>>(bufs[s & 1], bufs[(s + 1) & 1],
                                           wb, cb, b1, b2);
    }
    // NSTEP=60 even -> final state in g0
    softmax_out<<<(NPIX + 255) / 256, 256, 0, stream>>>(g0, out);
}